// Round 15
// baseline (41.426 us; speedup 1.0000x reference)
//
#include <hip/hip_runtime.h>

typedef float v4f __attribute__((ext_vector_type(4)));

// The 12 nonzero taps of the 23-tap halfband filter (even indices), center tap = 1.
constexpr float W12c[12] = {
    -1.20162964e-04f,    1.615524292e-03f, -1.0385513306e-02f,  4.3619155884e-02f,
    -1.45397186478e-01f, 6.1066818237e-01f, 6.1066818237e-01f, -1.45397186478e-01f,
     4.3619155884e-02f, -1.0385513306e-02f, 1.615524292e-03f,  -1.20162964e-04f
};

// Composite height weights over ww rows (ww = width-composited x rows).
// out[4k] = sum_u W12[u] ww[k-6+u]; out[4k+1] = sum_d ge[d] ww[k-8+d];
// out[4k+2] = ww[k];               out[4k+3] = sum_d go[d] ww[k-8+d].
struct GTabs { float ge[17]; float go[17]; };
constexpr GTabs make_gtabs() {
    GTabs t{};
    for (int d = 0; d < 17; ++d) { t.ge[d] = 0.f; t.go[d] = 0.f; }
    for (int v = 0; v < 6; ++v) { t.ge[v + 5] += W12c[2 * v]; t.go[v + 6] += W12c[2 * v + 1]; }
    for (int v = 0; v < 6; ++v)
        for (int u = 0; u < 12; ++u) {
            t.ge[v + u] += W12c[2 * v + 1] * W12c[u];
            t.go[v + u] += W12c[2 * v]     * W12c[u];
        }
    return t;
}
__device__ constexpr GTabs G = make_gtabs();

// Bijective XCD-chunking swizzle (grid % 8 == 0).
__device__ __forceinline__ int xcd_map(int bid, int nblk) {
    int cpx = nblk >> 3;
    return (bid & 7) * cpx + (bid >> 3);
}

// Fully fused, reordered 4x upsample: out = (H2 H1)(W2 W1)(x). R15 = R14 with
// split-phase pipeline A1 | (A2 ∥ D1) | D2: D1 reads ww rows <=31 while A2
// writes rows >=32 (disjoint, no barrier between) — stores flow during ~65%
// of the block instead of the last ~60%. Plain stores (R14: NT cost 12%).
__global__ __launch_bounds__(256) void k_fused(const float* __restrict__ x,
                                               float* __restrict__ out) {
    __shared__ float ww[48][132];   // rows (KQ-8 .. KQ+39) mod 160, 128 cols + pad

    int bid = xcd_map(blockIdx.x, gridDim.x);
    int ct = bid % 5, rt = (bid / 5) % 5, bc = bid / 25;
    int KQ = rt * 32;          // out-row quads KQ..KQ+31
    int MC0 = ct * 64;         // mid col base (out col base = 2*MC0)
    int WB = KQ - 8;           // ww row window base (pre-mod)
    int tid = threadIdx.x;

    // ---- width-composite row generator (verified R13/R14): ww[e][:] for
    // row (WB+e) mod 160, 16 out cols per item (e, g), g = 0..7.
    auto gen_ww = [&](int e, int g) {
        int m = WB + e; m = m < 0 ? m + 160 : (m >= 160 ? m - 160 : m);
        const float* xr = x + (bc * 160 + m) * 160;
        int XC0 = 32 * ct + 4 * g - 8;
        int qb0 = XC0 >> 2;            // floor(XC0/4)
        float flat[20];
#pragma unroll
        for (int b = 0; b < 5; ++b) {
            int bq = qb0 + b; bq = bq < 0 ? 0 : (bq > 39 ? 39 : bq);
            *(v4f*)(flat + 4 * b) = *(const v4f*)(xr + 4 * bq);
        }
        if (ct == 0 && g < 2) {        // W1 left pad: cols < 0 -> 0
#pragma unroll
            for (int p = 0; p < 8; ++p) flat[p] = (XC0 + p < 0) ? 0.f : flat[p];
        }
        float x159 = flat[19];         // = x[159] whenever right clamp occurred
        if (ct == 4 && g >= 6) {       // W1 right pad: cols > 159 -> x[159]
#pragma unroll
            for (int p = 12; p < 20; ++p) flat[p] = (XC0 + p > 159) ? x159 : flat[p];
        }
        float mcol[19];
#pragma unroll
        for (int t = 0; t < 9; ++t) {  // mid evens: 12-tap W1
            float acc = 0.f;
#pragma unroll
            for (int s = 0; s < 12; ++s) acc += W12c[s] * flat[t + s];
            mcol[2 * t + 1] = acc;
        }
#pragma unroll
        for (int t = 0; t < 10; ++t) mcol[2 * t] = flat[5 + t];   // copies
        if (ct == 4 && g >= 5) {       // stage-1 right copy corr (xi >= 154)
#pragma unroll
            for (int t = 0; t < 10; ++t) {
                int xi = XC0 + 5 + t;
                float c = 0.f;
#pragma unroll
                for (int s = 0; s < 12; ++s) if (xi + s >= 165) c += W12c[s];
                mcol[2 * t] += c * x159;
            }
        }
        float mid0 = mcol[5];          // = global mid col 0 when ct==0, g==0
        if (ct == 0 && g == 0) {       // W2 left pad: mid cols < 0 -> mid[0]
#pragma unroll
            for (int p = 0; p < 5; ++p) mcol[p] = mid0;
        }
        if (ct == 4 && g == 7) {       // W2 right pad: mid cols > 319 -> 0
#pragma unroll
            for (int p = 13; p < 19; ++p) mcol[p] = 0.f;
        }
        float oe[8], oo[8];
#pragma unroll
        for (int d = 0; d < 8; ++d) {
            float acc = 0.f;
#pragma unroll
            for (int s = 0; s < 12; ++s) acc += W12c[s] * mcol[d + s];
            oo[d] = acc;
            oe[d] = mcol[d + 5];
        }
        if (ct == 0 && g == 0) {       // W2 left copy corr (i <= 5)
#pragma unroll
            for (int d = 0; d < 6; ++d) {
                float c = 0.f;
#pragma unroll
                for (int s = 0; s < 12; ++s) if (d + s <= 5) c += W12c[s];
                oe[d] += c * mid0;
            }
        }
#pragma unroll
        for (int j = 0; j < 4; ++j) {
            v4f v;
            v.x = oe[2 * j];     v.y = oo[2 * j];
            v.z = oe[2 * j + 1]; v.w = oo[2 * j + 1];
            *(v4f*)(&ww[e][16 * g + 4 * j]) = v;
        }
    };

    int c4 = tid & 31, slot = tid >> 5;
    float* dbase = out + (size_t)bc * 640 * 640 + 2 * MC0 + 4 * c4;
    // Height-composite emitter for quad kk using 17-row window w = ww[kk..kk+16].
    auto emit_quad = [&](const v4f* w, int kk) {
        int k = KQ + kk;
        float* r0 = dbase + (size_t)(4 * k) * 640;
        v4f a = W12c[0] * w[2];
#pragma unroll
        for (int u = 1; u < 12; ++u) a += W12c[u] * w[u + 2];
        *(v4f*)(r0) = a;
        v4f b = G.ge[0] * w[0];
#pragma unroll
        for (int d = 1; d < 17; ++d) b += G.ge[d] * w[d];
        *(v4f*)(r0 + 640) = b;
        *(v4f*)(r0 + 1280) = w[8];
        v4f c = G.go[0] * w[0];
#pragma unroll
        for (int d = 1; d < 17; ++d) c += G.go[d] * w[d];
        *(v4f*)(r0 + 1920) = c;
    };

    // ---- Phase A1: ww rows 0..31 (256 items, exactly 1 per thread).
    gen_ww(tid >> 3, tid & 7);
    __syncthreads();

    // ---- Phase A2 ∥ D1 (no barrier between: A2 writes ww rows >=32, D1 reads <=31).
    if (tid < 128) {                   // A2 first so its global loads issue early
        gen_ww(32 + (tid >> 3), tid & 7);
    }
    {
        // D1: quads kk = 2*slot + q (0..15); window rows kk..kk+16 <= 31.
        v4f w[17];
#pragma unroll
        for (int t = 0; t < 17; ++t) w[t] = *(const v4f*)(&ww[2 * slot + t][4 * c4]);
        emit_quad(w, 2 * slot);
#pragma unroll
        for (int t = 0; t < 16; ++t) w[t] = w[t + 1];
        w[16] = *(const v4f*)(&ww[2 * slot + 17][4 * c4]);
        emit_quad(w, 2 * slot + 1);
    }
    __syncthreads();

    // ---- Phase D2: quads kk = 16 + 2*slot + q (16..31); window rows 16..47.
    {
        v4f w[17];
#pragma unroll
        for (int t = 0; t < 17; ++t) w[t] = *(const v4f*)(&ww[16 + 2 * slot + t][4 * c4]);
        emit_quad(w, 16 + 2 * slot);
#pragma unroll
        for (int t = 0; t < 16; ++t) w[t] = w[t + 1];
        w[16] = *(const v4f*)(&ww[16 + 2 * slot + 17][4 * c4]);
        emit_quad(w, 16 + 2 * slot + 1);
    }
}

extern "C" void kernel_launch(void* const* d_in, const int* in_sizes, int n_in,
                              void* d_out, int out_size, void* d_ws, size_t ws_size,
                              hipStream_t stream) {
    const float* x = (const float*)d_in[0];
    float* out = (float*)d_out;
    // 3200 blocks = 128 bc x 5 row-tiles x 5 col-tiles (d_ws unused)
    k_fused<<<3200, 256, 0, stream>>>(x, out);
}